// Round 12
// baseline (1010.134 us; speedup 1.0000x reference)
//
#include <hip/hip_runtime.h>

// GCN 3-layer encoder: bucket-binned edges + phase-sorted, LDS-accumulated
// layers. Buckets of 256 dst nodes; one block per bucket; edges packed
// (src<<8 | dstLocal) and counting-sorted by src-phase (16K-node = 2MB p2
// windows). Layer kernels accumulate into LDS (edge-parallel flat loops ->
// high MLP; round-11 evidence: node-serial phasing was latency-bound at
// 0.4TB/s despite FETCH at the 105MB XCD floor). All blocks co-resident
// (391 blocks, 3/CU) -> phases stay aligned across blocks, keeping the
// active p2 window L2-resident.
// Aggregation on the narrower side (A@(H W) = (A@H)@W); norm folded as
// p = dinv*h ; agg = sum p[src] ; out = dinv*(agg + p_self).

#define G_GRAPHS 128
#define BK_SHIFT 8
#define BK 256        // dst nodes per bucket
#define NB_MAX 512    // max buckets (n <= 131072)
#define PH_SHIFT 14   // 16384-src window per phase (2MB of p2)
#define NPH 8         // phase slots
#define L2PAD 33      // LDS row stride for layer2 accumulator

// K1: global bucket histogram (grid-stride, LDS-staged)
__global__ void hist_kernel(const int* __restrict__ dst, int* __restrict__ bcnt,
                            int E, int nb) {
    __shared__ int h[NB_MAX];
    for (int t = threadIdx.x; t < NB_MAX; t += blockDim.x) h[t] = 0;
    __syncthreads();
    for (int e = blockIdx.x * blockDim.x + threadIdx.x; e < E; e += gridDim.x * blockDim.x)
        atomicAdd(&h[dst[e] >> BK_SHIFT], 1);
    __syncthreads();
    for (int t = threadIdx.x; t < nb; t += blockDim.x)
        if (h[t]) atomicAdd(&bcnt[t], h[t]);
}

// K2: single-block exclusive scan of bucket counts -> boff, cursor (nb <= 512)
__global__ void bscan_kernel(const int* __restrict__ bcnt, int* __restrict__ boff,
                             int* __restrict__ cursor, int nb) {
    __shared__ int tmp[NB_MAX];
    int t = threadIdx.x;
    int v = (t < nb) ? bcnt[t] : 0;
    tmp[t] = v;
    __syncthreads();
    for (int off = 1; off < NB_MAX; off <<= 1) {
        int u = (t >= off) ? tmp[t - off] : 0;
        __syncthreads();
        tmp[t] += u;
        __syncthreads();
    }
    if (t < nb) {
        int excl = tmp[t] - v;
        boff[t] = excl;
        cursor[t] = excl;
    }
    if (t == nb - 1) boff[nb] = tmp[t];
}

// K3: bin edges into buckets with per-(block,bucket) chunked reservation.
__global__ void bin_kernel(const int* __restrict__ src, const int* __restrict__ dst,
                           int* __restrict__ cursor, unsigned* __restrict__ bedge,
                           int E, int nb, int chunk) {
    __shared__ int lcnt[NB_MAX];
    __shared__ int lbase[NB_MAX];
    int start = blockIdx.x * chunk;
    int end = min(start + chunk, E);
    for (int t = threadIdx.x; t < NB_MAX; t += blockDim.x) lcnt[t] = 0;
    __syncthreads();
    for (int e = start + threadIdx.x; e < end; e += blockDim.x)
        atomicAdd(&lcnt[dst[e] >> BK_SHIFT], 1);
    __syncthreads();
    for (int t = threadIdx.x; t < nb; t += blockDim.x) {
        int c = lcnt[t];
        lbase[t] = c ? atomicAdd(&cursor[t], c) : 0;
    }
    __syncthreads();
    for (int t = threadIdx.x; t < NB_MAX; t += blockDim.x) lcnt[t] = 0;
    __syncthreads();
    for (int e = start + threadIdx.x; e < end; e += blockDim.x) {
        int d = dst[e];
        int bk = d >> BK_SHIFT;
        int pos = lbase[bk] + atomicAdd(&lcnt[bk], 1);
        bedge[pos] = ((unsigned)src[e] << BK_SHIFT) | (unsigned)(d & (BK - 1));
    }
}

// K4: per-bucket 8-bin counting sort by src-phase -> bedge2 + eoff[b*8+x];
// fused per-node degree hist -> dinv + p1 = dinv*x (float4-padded).
__global__ __launch_bounds__(256) void phase_sort(
    const unsigned* __restrict__ bedge, const int* __restrict__ boff,
    const float* __restrict__ x, unsigned* __restrict__ bedge2,
    int* __restrict__ eoff, float* __restrict__ dinv, float* __restrict__ p1,
    int n, int E, int nb) {
    __shared__ int deghist[BK];
    __shared__ int phh[NPH];
    __shared__ int phc[NPH];
    int b = blockIdx.x;
    int beg = boff[b], end = boff[b + 1];
    int t = threadIdx.x;
    deghist[t] = 0;
    if (t < NPH) phh[t] = 0;
    __syncthreads();
    for (int e = beg + t; e < end; e += 256) {
        unsigned u = bedge[e];
        atomicAdd(&deghist[u & (BK - 1)], 1);
        atomicAdd(&phh[(u >> BK_SHIFT) >> PH_SHIFT], 1);
    }
    __syncthreads();
    if (t == 0) {
        int s = beg;
        for (int q = 0; q < NPH; ++q) {
            int c = phh[q];
            phc[q] = s;
            eoff[b * NPH + q] = s;
            s += c;
        }
    }
    if (b == 0 && t == 0) eoff[nb * NPH] = E;
    __syncthreads();
    int i = (b << BK_SHIFT) + t;
    if (i < n) {
        float di = rsqrtf((float)deghist[t] + 1.0f);
        dinv[i] = di;
        *reinterpret_cast<float4*>(p1 + 4 * (size_t)i) =
            make_float4(di * x[3 * i + 0], di * x[3 * i + 1], di * x[3 * i + 2], 0.0f);
    }
    for (int e = beg + t; e < end; e += 256) {
        unsigned u = bedge[e];
        int pos = atomicAdd(&phc[(u >> BK_SHIFT) >> PH_SHIFT], 1);
        bedge2[pos] = u;
    }
}

// ---- Layers (one block per bucket; LDS accumulate; edge-parallel) ---------

// K5: layer 1 — LDS acc 3-wide (stride 4), thread/edge gather of float4 p1
// rows, then per-node 3->32 transform, write p2.
__global__ __launch_bounds__(256) void layer1_bucket(
    const unsigned* __restrict__ bedge2, const int* __restrict__ eoff,
    const float* __restrict__ p1, const float* __restrict__ dinv,
    const float* __restrict__ W1, const float* __restrict__ b1,
    float* __restrict__ p2, int n) {
    __shared__ float acc[BK * 4];
    __shared__ float w[96];
    __shared__ float bb[32];
    for (int t = threadIdx.x; t < BK * 4; t += 256) acc[t] = 0.f;
    for (int t = threadIdx.x; t < 96; t += 256) w[t] = W1[t];
    for (int t = threadIdx.x; t < 32; t += 256) bb[t] = b1[t];
    __syncthreads();
    int b = blockIdx.x;
    int beg = eoff[b * NPH], end = eoff[b * NPH + NPH];
    for (int e = beg + threadIdx.x; e < end; e += 256) {
        unsigned u = bedge2[e];
        int s = u >> BK_SHIFT;
        int dl = u & (BK - 1);
        const float4 v = *reinterpret_cast<const float4*>(p1 + 4 * (size_t)s);
        atomicAdd(&acc[dl * 4 + 0], v.x);
        atomicAdd(&acc[dl * 4 + 1], v.y);
        atomicAdd(&acc[dl * 4 + 2], v.z);
    }
    __syncthreads();
    int k = threadIdx.x;
    int i = (b << BK_SHIFT) + k;
    if (i >= n) return;
    float d = dinv[i];
    const float4 sf = *reinterpret_cast<const float4*>(p1 + 4 * (size_t)i);
    float s0 = d * (acc[k * 4 + 0] + sf.x);
    float s1 = d * (acc[k * 4 + 1] + sf.y);
    float s2 = d * (acc[k * 4 + 2] + sf.z);
#pragma unroll
    for (int q = 0; q < 8; ++q) {
        float o[4];
#pragma unroll
        for (int c = 0; c < 4; ++c) {
            int j = q * 4 + c;
            float h = fmaf(s0, w[j], fmaf(s1, w[32 + j], fmaf(s2, w[64 + j], bb[j])));
            o[c] = d * fmaxf(h, 0.0f);
        }
        *reinterpret_cast<float4*>(p2 + 32 * (size_t)i + 4 * q) =
            make_float4(o[0], o[1], o[2], o[3]);
    }
}

// K6: layer 2 — phased edge-parallel gather into LDS acc[256][33]; 8 threads
// per edge (one float4 part each); per-phase barrier keeps the block inside
// one 2MB p2 window; all blocks co-resident -> windows aligned across CUs.
// Epilogue: per-node 32->64 relu -> 64->2, write p3.
__global__ __launch_bounds__(512) void layer2_bucket(
    const unsigned* __restrict__ bedge2, const int* __restrict__ eoff,
    const float* __restrict__ p2, const float* __restrict__ dinv,
    const float* __restrict__ W2, const float* __restrict__ b2,
    const float* __restrict__ W3, float* __restrict__ p3, int n) {
    __shared__ float acc[BK * L2PAD];   // 33.8 KB
    __shared__ float w2[32 * 64];
    __shared__ float b2s[64];
    __shared__ float w3[128];
    for (int t = threadIdx.x; t < BK * L2PAD; t += 512) acc[t] = 0.f;
    for (int t = threadIdx.x; t < 32 * 64; t += 512) w2[t] = W2[t];
    if (threadIdx.x < 64)  b2s[threadIdx.x] = b2[threadIdx.x];
    if (threadIdx.x < 128) w3[threadIdx.x] = W3[threadIdx.x];
    __syncthreads();
    int b = blockIdx.x;
    int part = threadIdx.x & 7;
    for (int x = 0; x < NPH; ++x) {
        int s0 = eoff[b * NPH + x];
        int s1 = eoff[b * NPH + x + 1];
        for (int e = s0 + (threadIdx.x >> 3); e < s1; e += 64) {
            unsigned u = bedge2[e];
            int s = u >> BK_SHIFT;
            int dl = u & (BK - 1);
            const float4 v =
                *reinterpret_cast<const float4*>(p2 + 32 * (size_t)s + 4 * part);
            float* a = &acc[dl * L2PAD + 4 * part];
            atomicAdd(a + 0, v.x);
            atomicAdd(a + 1, v.y);
            atomicAdd(a + 2, v.z);
            atomicAdd(a + 3, v.w);
        }
        __syncthreads();  // stay inside the current 2MB p2 window
    }
    int k = threadIdx.x;
    if (k >= BK) return;
    int i = (b << BK_SHIFT) + k;
    if (i >= n) return;
    float d = dinv[i];
    float s[32];
#pragma unroll
    for (int c = 0; c < 32; ++c) s[c] = d * (acc[k * L2PAD + c] + p2[32 * (size_t)i + c]);
    float a0 = 0.f, a1 = 0.f;
#pragma unroll 4
    for (int j = 0; j < 64; ++j) {
        float h = b2s[j];
#pragma unroll
        for (int c = 0; c < 32; ++c) h = fmaf(s[c], w2[c * 64 + j], h);
        h = fmaxf(h, 0.0f);
        a0 = fmaf(h, w3[2 * j + 0], a0);
        a1 = fmaf(h, w3[2 * j + 1], a1);
    }
    p3[2 * (size_t)i + 0] = d * a0;
    p3[2 * (size_t)i + 1] = d * a1;
}

// K7: layer 3 — LDS acc 2-wide (stride 3), thread/edge; epilogue + mean-pool.
__global__ __launch_bounds__(256) void layer3_pool(
    const unsigned* __restrict__ bedge2, const int* __restrict__ eoff,
    const float* __restrict__ p3, const float* __restrict__ dinv,
    const int* __restrict__ batch, const float* __restrict__ b3,
    float* __restrict__ sums, float* __restrict__ cnt, int n) {
    __shared__ float acc[BK * 3];
    __shared__ float ls[G_GRAPHS * 2];
    __shared__ float lc[G_GRAPHS];
    for (int t = threadIdx.x; t < BK * 3; t += 256) acc[t] = 0.f;
    for (int t = threadIdx.x; t < G_GRAPHS * 2; t += 256) ls[t] = 0.f;
    for (int t = threadIdx.x; t < G_GRAPHS; t += 256) lc[t] = 0.f;
    __syncthreads();
    int b = blockIdx.x;
    int beg = eoff[b * NPH], end = eoff[b * NPH + NPH];
    for (int e = beg + threadIdx.x; e < end; e += 256) {
        unsigned u = bedge2[e];
        int s = u >> BK_SHIFT;
        int dl = u & (BK - 1);
        const float2 v = *reinterpret_cast<const float2*>(p3 + 2 * (size_t)s);
        atomicAdd(&acc[dl * 3 + 0], v.x);
        atomicAdd(&acc[dl * 3 + 1], v.y);
    }
    __syncthreads();
    int k = threadIdx.x;
    int i = (b << BK_SHIFT) + k;
    if (i < n) {
        float d = dinv[i];
        float v0 = fmaf(d, acc[k * 3 + 0] + p3[2 * (size_t)i + 0], b3[0]);
        float v1 = fmaf(d, acc[k * 3 + 1] + p3[2 * (size_t)i + 1], b3[1]);
        int g = batch[i];
        atomicAdd(&ls[2 * g + 0], v0);
        atomicAdd(&ls[2 * g + 1], v1);
        atomicAdd(&lc[g], 1.0f);
    }
    __syncthreads();
    for (int g = threadIdx.x; g < G_GRAPHS; g += 256) {
        float c = lc[g];
        if (c != 0.0f) {
            atomicAdd(&sums[2 * g + 0], ls[2 * g + 0]);
            atomicAdd(&sums[2 * g + 1], ls[2 * g + 1]);
            atomicAdd(&cnt[g], c);
        }
    }
}

__global__ void finalize_kernel(const float* __restrict__ sums, const float* __restrict__ cnt,
                                float* __restrict__ out) {
    int g = threadIdx.x;
    if (g < G_GRAPHS) {
        float c = fmaxf(cnt[g], 1.0f);
        out[2 * g + 0] = sums[2 * g + 0] / c;
        out[2 * g + 1] = sums[2 * g + 1] / c;
    }
}

// ---- Launch ---------------------------------------------------------------

extern "C" void kernel_launch(void* const* d_in, const int* in_sizes, int n_in,
                              void* d_out, int out_size, void* d_ws, size_t ws_size,
                              hipStream_t stream) {
    const float* x     = (const float*)d_in[0];
    const int*   ei    = (const int*)d_in[1];
    const int*   batch = (const int*)d_in[2];
    const float* W1    = (const float*)d_in[3];
    const float* b1    = (const float*)d_in[4];
    const float* W2    = (const float*)d_in[5];
    const float* b2    = (const float*)d_in[6];
    const float* W3    = (const float*)d_in[7];
    const float* b3    = (const float*)d_in[8];
    float* out = (float*)d_out;

    const int n = in_sizes[0] / 3;
    const int E = in_sizes[1] / 2;
    const int* src = ei;
    const int* dst = ei + E;
    const int nb = (n + BK - 1) >> BK_SHIFT;   // 391 for n=100000

    // Workspace layout (4-byte words). Zeroed prefix: bcnt + sums + cnt.
    int* w = (int*)d_ws;
    size_t off = 0;
    auto take = [&](size_t words) { size_t o = off; off = (off + words + 3) & ~(size_t)3; return o; };
    int*      bcnt   = w + take(NB_MAX);               // 512 (zeroed)
    float*    sums   = (float*)(w + take(2 * G_GRAPHS));  // zeroed
    float*    cnt    = (float*)(w + take(G_GRAPHS));      // zeroed
    int*      boff   = w + take(NB_MAX + 1);
    int*      cursor = w + take(NB_MAX);
    int*      eoff   = w + take((size_t)nb * NPH + 4);
    unsigned* bedge2 = (unsigned*)(w + take(E));
    float*    dinv   = (float*)(w + take(n));
    float*    p1     = (float*)(w + take(4 * (size_t)n));
    off = (off + 31) & ~(size_t)31;  // align p2 rows to 128B
    float*    p2     = (float*)(w + take(32 * (size_t)n));
    float*    p3     = (float*)(w + take(2 * (size_t)n));
    // bedge (pre-sort) aliases p2: dead before layer1 writes p2. 32n >= E here.
    unsigned* bedge  = (32 * (size_t)n >= (size_t)E) ? (unsigned*)p2 : (unsigned*)(w + take(E));

    hipMemsetAsync(d_ws, 0, (NB_MAX + 3 * G_GRAPHS) * 4, stream);

    const int B = 256;
    const int BINB = 1024;
    const int chunk = (E + BINB - 1) / BINB;

    hist_kernel<<<BINB, B, 0, stream>>>(dst, bcnt, E, nb);
    bscan_kernel<<<1, NB_MAX, 0, stream>>>(bcnt, boff, cursor, nb);
    bin_kernel<<<BINB, B, 0, stream>>>(src, dst, cursor, bedge, E, nb, chunk);
    phase_sort<<<nb, B, 0, stream>>>(bedge, boff, x, bedge2, eoff, dinv, p1, n, E, nb);
    layer1_bucket<<<nb, B, 0, stream>>>(bedge2, eoff, p1, dinv, W1, b1, p2, n);
    layer2_bucket<<<nb, 512, 0, stream>>>(bedge2, eoff, p2, dinv, W2, b2, W3, p3, n);
    layer3_pool<<<nb, B, 0, stream>>>(bedge2, eoff, p3, dinv, batch, b3, sums, cnt, n);
    finalize_kernel<<<1, 128, 0, stream>>>(sums, cnt, out);
}

// Round 14
// 374.587 us; speedup vs baseline: 2.6967x; 2.6967x over previous
//
#include <hip/hip_runtime.h>
#include <hip/hip_fp16.h>

// GCN 3-layer encoder: bucket-binned CSR build + flat wave-gather layers.
// Round-7 structure (best measured: 394us) with p2 stored FP16:
// layer-2's gather is bound by bytes through L3 (294MB @ ~2.3TB/s = 129us;
// rounds 8-12 showed scheduling can't beat this without killing MLP), so
// halve the row size: 32xfp16 = 64B = one cache line. Accumulation stays
// fp32. k-loop 2x unrolled for extra loads in flight.
// Aggregation on the narrower side (A@(H W) = (A@H)@W); norm folded as
// p = dinv*h ; agg = sum p[src] ; out = dinv*(agg + p_self).

#define G_GRAPHS 128
#define BK_SHIFT 9
#define BK 512       // dst nodes per bucket
#define NB_MAX 256   // max buckets

// K1: global bucket histogram (grid-stride, LDS-staged)
__global__ void hist_kernel(const int* __restrict__ dst, int* __restrict__ bcnt,
                            int E, int nb) {
    __shared__ int h[NB_MAX];
    for (int t = threadIdx.x; t < NB_MAX; t += blockDim.x) h[t] = 0;
    __syncthreads();
    for (int e = blockIdx.x * blockDim.x + threadIdx.x; e < E; e += gridDim.x * blockDim.x)
        atomicAdd(&h[dst[e] >> BK_SHIFT], 1);
    __syncthreads();
    for (int t = threadIdx.x; t < nb; t += blockDim.x)
        if (h[t]) atomicAdd(&bcnt[t], h[t]);
}

// K2: single-block exclusive scan of bucket counts -> boff, cursor (nb <= 256)
__global__ void bscan_kernel(const int* __restrict__ bcnt, int* __restrict__ boff,
                             int* __restrict__ cursor, int nb) {
    __shared__ int tmp[NB_MAX];
    int t = threadIdx.x;
    int v = (t < nb) ? bcnt[t] : 0;
    tmp[t] = v;
    __syncthreads();
    for (int off = 1; off < NB_MAX; off <<= 1) {
        int u = (t >= off) ? tmp[t - off] : 0;
        __syncthreads();
        tmp[t] += u;
        __syncthreads();
    }
    if (t < nb) {
        int excl = tmp[t] - v;
        boff[t] = excl;
        cursor[t] = excl;
    }
    if (t == nb - 1) boff[nb] = tmp[t];
}

// K3: bin edges into buckets with per-(block,bucket) chunked reservation.
__global__ void bin_kernel(const int* __restrict__ src, const int* __restrict__ dst,
                           int* __restrict__ cursor, unsigned* __restrict__ bedge,
                           int E, int nb, int chunk) {
    __shared__ int lcnt[NB_MAX];
    __shared__ int lbase[NB_MAX];
    int start = blockIdx.x * chunk;
    int end = min(start + chunk, E);
    for (int t = threadIdx.x; t < NB_MAX; t += blockDim.x) lcnt[t] = 0;
    __syncthreads();
    for (int e = start + threadIdx.x; e < end; e += blockDim.x)
        atomicAdd(&lcnt[dst[e] >> BK_SHIFT], 1);
    __syncthreads();
    for (int t = threadIdx.x; t < nb; t += blockDim.x) {
        int c = lcnt[t];
        lbase[t] = c ? atomicAdd(&cursor[t], c) : 0;
    }
    __syncthreads();
    for (int t = threadIdx.x; t < NB_MAX; t += blockDim.x) lcnt[t] = 0;
    __syncthreads();
    for (int e = start + threadIdx.x; e < end; e += blockDim.x) {
        int d = dst[e];
        int bk = d >> BK_SHIFT;
        int pos = lbase[bk] + atomicAdd(&lcnt[bk], 1);
        bedge[pos] = ((unsigned)src[e] << BK_SHIFT) | (unsigned)(d & (BK - 1));
    }
}

// K4: per-bucket counting sort -> dst-sorted CSR (src payload) + woff + dinv.
// (p1 is written by a separate prescale kernel so bedge can alias the
// p1/p2h/p3 region.)
__global__ __launch_bounds__(512) void sort_build(
    const unsigned* __restrict__ bedge, const int* __restrict__ boff,
    int* __restrict__ csr, int* __restrict__ woff, float* __restrict__ dinv,
    int n, int E) {
    __shared__ int hist[BK];
    __shared__ int scan[BK];
    __shared__ int cur[BK];
    int b = blockIdx.x;
    int beg = boff[b], end = boff[b + 1];
    int t = threadIdx.x;
    hist[t] = 0;
    __syncthreads();
    for (int e = beg + t; e < end; e += 512)
        atomicAdd(&hist[bedge[e] & (BK - 1)], 1);
    __syncthreads();
    int v = hist[t];
    scan[t] = v;
    __syncthreads();
    for (int off = 1; off < BK; off <<= 1) {
        int u = (t >= off) ? scan[t - off] : 0;
        __syncthreads();
        scan[t] += u;
        __syncthreads();
    }
    int excl = scan[t] - v;
    int i = (b << BK_SHIFT) + t;
    if (i < n) {
        woff[i] = beg + excl;
        dinv[i] = rsqrtf((float)v + 1.0f);
    }
    if (b == 0 && t == 0) woff[n] = E;
    cur[t] = beg + excl;
    __syncthreads();
    for (int e = beg + t; e < end; e += 512) {
        unsigned u = bedge[e];
        int pos = atomicAdd(&cur[u & (BK - 1)], 1);
        csr[pos] = (int)(u >> BK_SHIFT);
    }
}

// K5: p1[i] = dinv[i] * x[i], float4-padded
__global__ void prescale_kernel(const float* __restrict__ x, const float* __restrict__ dinv,
                                float* __restrict__ p1, int n) {
    int i = blockIdx.x * blockDim.x + threadIdx.x;
    if (i >= n) return;
    float d = dinv[i];
    *reinterpret_cast<float4*>(p1 + 4 * (size_t)i) =
        make_float4(d * x[3 * i + 0], d * x[3 * i + 1], d * x[3 * i + 2], 0.0f);
}

__device__ __forceinline__ unsigned pack_half2(float a, float b) {
    __half2 h = __float22half2_rn(make_float2(a, b));
    return *reinterpret_cast<unsigned*>(&h);
}

__device__ __forceinline__ float4 load_half4(const __half* p) {
    uint2 q = *reinterpret_cast<const uint2*>(p);
    float2 fa = __half22float2(*reinterpret_cast<__half2*>(&q.x));
    float2 fb = __half22float2(*reinterpret_cast<__half2*>(&q.y));
    return make_float4(fa.x, fa.y, fb.x, fb.y);
}

// K6: thread/node: gather float4 p1 rows, s = dinv*(sum + self),
// p2h = fp16( dinv*relu(s@W1+b1) )  (64B rows, uint4 stores)
__global__ void layer1_fused(const int* __restrict__ csr, const int* __restrict__ woff,
                             const float* __restrict__ p1, const float* __restrict__ dinv,
                             const float* __restrict__ W1, const float* __restrict__ b1,
                             __half* __restrict__ p2h, int n) {
    __shared__ float w[96];
    __shared__ float bb[32];
    for (int t = threadIdx.x; t < 96; t += blockDim.x) w[t] = W1[t];
    for (int t = threadIdx.x; t < 32; t += blockDim.x) bb[t] = b1[t];
    __syncthreads();
    int i = blockIdx.x * blockDim.x + threadIdx.x;
    if (i >= n) return;
    int beg = woff[i], end = woff[i + 1];
    float s0 = 0.f, s1 = 0.f, s2 = 0.f;
    for (int k = beg; k < end; ++k) {
        int s = csr[k];
        const float4 v = *reinterpret_cast<const float4*>(p1 + 4 * (size_t)s);
        s0 += v.x; s1 += v.y; s2 += v.z;
    }
    float d = dinv[i];
    const float4 sf = *reinterpret_cast<const float4*>(p1 + 4 * (size_t)i);
    s0 = d * (s0 + sf.x);
    s1 = d * (s1 + sf.y);
    s2 = d * (s2 + sf.z);
#pragma unroll
    for (int q = 0; q < 4; ++q) {
        float o[8];
#pragma unroll
        for (int c = 0; c < 8; ++c) {
            int j = q * 8 + c;
            float h = fmaf(s0, w[j], fmaf(s1, w[32 + j], fmaf(s2, w[64 + j], bb[j])));
            o[c] = d * fmaxf(h, 0.0f);
        }
        uint4 pk;
        pk.x = pack_half2(o[0], o[1]);
        pk.y = pack_half2(o[2], o[3]);
        pk.z = pack_half2(o[4], o[5]);
        pk.w = pack_half2(o[6], o[7]);
        *reinterpret_cast<uint4*>(p2h + 32 * (size_t)i + 8 * q) = pk;
    }
}

// K7: wave/node: gather 32xfp16 rows (8 lanes x 8B, 8 edges in flight,
// k-loop 2x unrolled -> 2 independent row loads per lane), fp32 accumulate,
// slot-reduce via shfl_xor, fuse 32->64 relu and 64->2 transform in-wave.
__global__ __launch_bounds__(256) void gather2_layer2(
    const int* __restrict__ csr, const int* __restrict__ woff,
    const __half* __restrict__ p2h, const float* __restrict__ dinv,
    const float* __restrict__ W2, const float* __restrict__ b2,
    const float* __restrict__ W3, float* __restrict__ p3, int n) {
    __shared__ float w2[32 * 64];
    __shared__ float b2s[64];
    __shared__ float w3[128];
    for (int t = threadIdx.x; t < 32 * 64; t += 256) w2[t] = W2[t];
    if (threadIdx.x < 64)  b2s[threadIdx.x] = b2[threadIdx.x];
    if (threadIdx.x < 128) w3[threadIdx.x] = W3[threadIdx.x];
    __syncthreads();

    int lane = threadIdx.x & 63;
    int i = blockIdx.x * 4 + (threadIdx.x >> 6);
    if (i >= n) return;  // wave-uniform

    int beg = woff[i];
    int dg  = woff[i + 1] - beg;
    int part = lane & 7;   // which 4-element chunk of the 32-half row
    int slot = lane >> 3;  // edge slot 0..7
    float4 acc = {0.f, 0.f, 0.f, 0.f};
    int k = slot;
    for (; k + 8 < dg; k += 16) {  // 2 rows in flight per lane
        int sA = csr[beg + k];
        int sB = csr[beg + k + 8];
        float4 vA = load_half4(p2h + 32 * (size_t)sA + 4 * part);
        float4 vB = load_half4(p2h + 32 * (size_t)sB + 4 * part);
        acc.x += vA.x + vB.x;
        acc.y += vA.y + vB.y;
        acc.z += vA.z + vB.z;
        acc.w += vA.w + vB.w;
    }
    if (k < dg) {
        int s = csr[beg + k];
        float4 v = load_half4(p2h + 32 * (size_t)s + 4 * part);
        acc.x += v.x; acc.y += v.y; acc.z += v.z; acc.w += v.w;
    }
#pragma unroll
    for (int m = 8; m <= 32; m <<= 1) {
        acc.x += __shfl_xor(acc.x, m, 64);
        acc.y += __shfl_xor(acc.y, m, 64);
        acc.z += __shfl_xor(acc.z, m, 64);
        acc.w += __shfl_xor(acc.w, m, 64);
    }
    float d = dinv[i];
    {   // add self row, scale by dinv
        const float4 v = load_half4(p2h + 32 * (size_t)i + 4 * part);
        acc.x = d * (acc.x + v.x);
        acc.y = d * (acc.y + v.y);
        acc.z = d * (acc.z + v.z);
        acc.w = d * (acc.w + v.w);
    }
    // lane j computes h2[j]; parts of s live on lanes 0..7
    int j = lane;
    float h = b2s[j];
#pragma unroll
    for (int p = 0; p < 8; ++p) {
        float s0 = __shfl(acc.x, p, 64);
        float s1 = __shfl(acc.y, p, 64);
        float s2 = __shfl(acc.z, p, 64);
        float s3 = __shfl(acc.w, p, 64);
        h = fmaf(s0, w2[(4 * p + 0) * 64 + j], h);
        h = fmaf(s1, w2[(4 * p + 1) * 64 + j], h);
        h = fmaf(s2, w2[(4 * p + 2) * 64 + j], h);
        h = fmaf(s3, w2[(4 * p + 3) * 64 + j], h);
    }
    h = fmaxf(h, 0.0f);
    float a0 = h * w3[2 * j + 0];
    float a1 = h * w3[2 * j + 1];
#pragma unroll
    for (int m = 1; m < 64; m <<= 1) {
        a0 += __shfl_xor(a0, m, 64);
        a1 += __shfl_xor(a1, m, 64);
    }
    if (lane == 0) {
        p3[2 * (size_t)i + 0] = d * a0;
        p3[2 * (size_t)i + 1] = d * a1;
    }
}

// K8: thread/node: gather 2-wide rows, epilogue + mean-pool (LDS bins)
__global__ void layer3_pool(const int* __restrict__ csr, const int* __restrict__ woff,
                            const float* __restrict__ p3, const float* __restrict__ dinv,
                            const int* __restrict__ batch, const float* __restrict__ b3,
                            float* __restrict__ sums, float* __restrict__ cnt, int n) {
    __shared__ float ls[G_GRAPHS * 2];
    __shared__ float lc[G_GRAPHS];
    for (int t = threadIdx.x; t < G_GRAPHS * 2; t += blockDim.x) ls[t] = 0.0f;
    for (int t = threadIdx.x; t < G_GRAPHS; t += blockDim.x) lc[t] = 0.0f;
    __syncthreads();
    int i = blockIdx.x * blockDim.x + threadIdx.x;
    if (i < n) {
        int beg = woff[i], end = woff[i + 1];
        float a0 = 0.f, a1 = 0.f;
        for (int k = beg; k < end; ++k) {
            int s = csr[k];
            a0 += p3[2 * (size_t)s + 0];
            a1 += p3[2 * (size_t)s + 1];
        }
        float d = dinv[i];
        float v0 = fmaf(d, a0 + p3[2 * (size_t)i + 0], b3[0]);
        float v1 = fmaf(d, a1 + p3[2 * (size_t)i + 1], b3[1]);
        int g = batch[i];
        atomicAdd(&ls[2 * g + 0], v0);
        atomicAdd(&ls[2 * g + 1], v1);
        atomicAdd(&lc[g], 1.0f);
    }
    __syncthreads();
    for (int g = threadIdx.x; g < G_GRAPHS; g += blockDim.x) {
        float c = lc[g];
        if (c != 0.0f) {
            atomicAdd(&sums[2 * g + 0], ls[2 * g + 0]);
            atomicAdd(&sums[2 * g + 1], ls[2 * g + 1]);
            atomicAdd(&cnt[g], c);
        }
    }
}

__global__ void finalize_kernel(const float* __restrict__ sums, const float* __restrict__ cnt,
                                float* __restrict__ out) {
    int g = threadIdx.x;
    if (g < G_GRAPHS) {
        float c = fmaxf(cnt[g], 1.0f);
        out[2 * g + 0] = sums[2 * g + 0] / c;
        out[2 * g + 1] = sums[2 * g + 1] / c;
    }
}

// ---- Launch ---------------------------------------------------------------

extern "C" void kernel_launch(void* const* d_in, const int* in_sizes, int n_in,
                              void* d_out, int out_size, void* d_ws, size_t ws_size,
                              hipStream_t stream) {
    const float* x     = (const float*)d_in[0];
    const int*   ei    = (const int*)d_in[1];
    const int*   batch = (const int*)d_in[2];
    const float* W1    = (const float*)d_in[3];
    const float* b1    = (const float*)d_in[4];
    const float* W2    = (const float*)d_in[5];
    const float* b2    = (const float*)d_in[6];
    const float* W3    = (const float*)d_in[7];
    const float* b3    = (const float*)d_in[8];
    float* out = (float*)d_out;

    const int n = in_sizes[0] / 3;
    const int E = in_sizes[1] / 2;
    const int* src = ei;
    const int* dst = ei + E;
    const int nb = (n + BK - 1) >> BK_SHIFT;

    // Workspace layout (4-byte words). Zeroed prefix: bcnt + sums + cnt.
    int* w = (int*)d_ws;
    size_t off = 0;
    auto take = [&](size_t words) { size_t o = off; off = (off + words + 3) & ~(size_t)3; return o; };
    int*      bcnt   = w + take(512);
    float*    sums   = (float*)(w + take(2 * G_GRAPHS));
    float*    cnt    = (float*)(w + take(G_GRAPHS));
    int*      boff   = w + take(NB_MAX + 1);
    int*      cursor = w + take(NB_MAX);
    int*      csr    = w + take(E);
    int*      woff   = w + take((size_t)n + 1);
    float*    dinv   = (float*)(w + take(n));
    off = (off + 15) & ~(size_t)15;  // 64B-align the aliased region
    // Aliased region R: bedge (E words, live bin->sort_build) overlays
    // p1 (4n) + p2h (16n) + p3 (2n) = 22n words (all written after
    // sort_build). Requires E >= 22n (holds: E=32n) else take extra.
    size_t rwords = ((size_t)E > 22 * (size_t)n + 16) ? (size_t)E : 22 * (size_t)n + 16;
    int*      R      = w + take(rwords);
    unsigned* bedge  = (unsigned*)R;
    float*    p1     = (float*)R;
    size_t p2h_off = (4 * (size_t)n + 15) & ~(size_t)15;
    __half*   p2h    = (__half*)(R + p2h_off);
    float*    p3     = (float*)(R + p2h_off + 16 * (size_t)n);

    hipMemsetAsync(d_ws, 0, 896 * 4, stream);

    const int B = 256;
    const int gridN = (n + B - 1) / B;
    const int BINB = 1024;
    const int chunk = (E + BINB - 1) / BINB;

    hist_kernel<<<BINB, B, 0, stream>>>(dst, bcnt, E, nb);
    bscan_kernel<<<1, NB_MAX, 0, stream>>>(bcnt, boff, cursor, nb);
    bin_kernel<<<BINB, B, 0, stream>>>(src, dst, cursor, bedge, E, nb, chunk);
    sort_build<<<nb, BK, 0, stream>>>(bedge, boff, csr, woff, dinv, n, E);
    prescale_kernel<<<gridN, B, 0, stream>>>(x, dinv, p1, n);
    layer1_fused<<<gridN, B, 0, stream>>>(csr, woff, p1, dinv, W1, b1, p2h, n);
    gather2_layer2<<<(n + 3) / 4, 256, 0, stream>>>(csr, woff, p2h, dinv, W2, b2, W3, p3, n);
    layer3_pool<<<gridN, B, 0, stream>>>(csr, woff, p3, dinv, batch, b3, sums, cnt, n);
    finalize_kernel<<<1, 128, 0, stream>>>(sums, cnt, out);
}